// Round 13
// baseline (89.634 us; speedup 1.0000x reference)
//
#include <hip/hip_runtime.h>
#include <math.h>

#define BS 8
#define CIN 64
#define COUT 64
#define SDIM 512
#define NBANK 4
#define DSZ 32
#define SPATIAL (DSZ*DSZ*DSZ)
#define NTAP 27
#define CH 8                   // ic per chunk
#define NCH 8                  // chunks
#define NST 14                 // K=16 steps per chunk (27 taps + 1 pad half)
// xP slab (per b,ch): 1124 rows x 33 texels (texel = 16B = 8 ic bf16)
#define SLABTEX (1124*33)
#define WINTEX 3301            // full-plane 3-z window
#define XBUFT 3304             // LDS X buffer texels (padded)
#define ABUFT 1792             // LDS A buffer texels: 14 steps * 128
#define XP_TEXELS (64*SLABTEX)
constexpr float EPS = 1e-8f;

typedef short bf16x8 __attribute__((ext_vector_type(8)));
typedef float f32x16 __attribute__((ext_vector_type(16)));

__device__ __forceinline__ unsigned pack2(float a, float b) {
    unsigned ua = __float_as_uint(a);
    unsigned ub = __float_as_uint(b);
    ua = (ua + 0x7fffu + ((ua >> 16) & 1u)) >> 16;
    ub = (ub + 0x7fffu + ((ub >> 16) & 1u)) & 0xffff0000u;
    return ua | ub;
}
__device__ __forceinline__ unsigned short bf16r(float f) {
    unsigned u = __float_as_uint(f);
    u = (u + 0x7fffu + ((u >> 16) & 1u)) >> 16;
    return (unsigned short)u;
}
__device__ __forceinline__ void gload_lds16(const int4* g, int4* l) {
    __builtin_amdgcn_global_load_lds(
        (const __attribute__((address_space(1))) unsigned int*)(const void*)g,
        (__attribute__((address_space(3))) unsigned int*)(void*)l, 16, 0, 0);
}

// ---------------------------------------------------------------------------
// prep_fused: blocks [0,128): weights (+inline style); [128,128+2176): xform.
// A K-step ordering (dy-phase structure for B-fragment reuse in conv):
//   tap t: dz=t/9, dy=(t%9)/3, dx=t%3, j=dz*3+dx.
//   j<8 : m = 3*(j>>1)+dy, h = j&1          (cols s=0..3, phases dy=0..2)
//   j==8: dy0 -> (m=12,h=0); dy1 -> (m=12,h=1); dy2 -> (m=13,h=0)
//   (m=13,h=1) = zero pad.
// A texel = ((b*8+c)*14 + m)*128 + (oc>>5)*64 + h*32 + (oc&31); elem = ic&7.
// ---------------------------------------------------------------------------
__global__ __launch_bounds__(256) void prep_fused(
        const float* __restrict__ x,
        const float* __restrict__ w,
        const float* __restrict__ filter_w,
        const float* __restrict__ filter_b,
        const float* __restrict__ mod_w,
        const float* __restrict__ mod_b,
        const float* __restrict__ bank,
        int4* __restrict__ xP,
        unsigned short* __restrict__ wA3) {
    const int gid = blockIdx.x;
    const int t   = threadIdx.x;

    if (gid < 128) {
        const int b   = gid >> 4;
        const int oc  = (gid & 15) * 4 + (t >> 6);
        const int ic  = t & 63;
        const float* wb = w + b * SDIM;

        float fw[NBANK];
#pragma unroll
        for (int n = 0; n < NBANK; ++n) {
            float p = 0.0f;
            const float* fr = filter_w + n * SDIM;
#pragma unroll
            for (int k = 0; k < 8; ++k) p += wb[ic + 64 * k] * fr[ic + 64 * k];
#pragma unroll
            for (int off = 32; off >= 1; off >>= 1) p += __shfl_xor(p, off, 64);
            fw[n] = p + filter_b[n];
        }
        float mx = fmaxf(fmaxf(fw[0], fw[1]), fmaxf(fw[2], fw[3]));
        float se = 0.0f;
#pragma unroll
        for (int n = 0; n < NBANK; ++n) { fw[n] = expf(fw[n] - mx); se += fw[n]; }
        const float inv = 1.0f / se;
        const float f0 = fw[0] * inv, f1 = fw[1] * inv, f2 = fw[2] * inv, f3 = fw[3] * inv;

        float m = mod_b[ic];
        {
            const float4* wv4 = (const float4*)wb;
            const float4* mr4 = (const float4*)(mod_w + ic * SDIM);
            for (int j = 0; j < SDIM / 4; ++j) {
                float4 a = wv4[j], c = mr4[j];
                m += a.x * c.x + a.y * c.y + a.z * c.z + a.w * c.w;
            }
        }

        const float* b0 = bank + (size_t)((0 * COUT + oc) * CIN + ic) * NTAP;
        const float* b1 = bank + (size_t)((1 * COUT + oc) * CIN + ic) * NTAP;
        const float* b2 = bank + (size_t)((2 * COUT + oc) * CIN + ic) * NTAP;
        const float* b3 = bank + (size_t)((3 * COUT + oc) * CIN + ic) * NTAP;

        float v[NTAP];
        float ss = 0.0f;
#pragma unroll
        for (int k = 0; k < NTAP; ++k) {
            float tv = f0 * b0[k] + f1 * b1[k] + f2 * b2[k] + f3 * b3[k];
            tv *= m;
            v[k] = tv;
            ss += tv * tv;
        }
#pragma unroll
        for (int off = 32; off >= 1; off >>= 1) ss += __shfl_xor(ss, off, 64);
        const float d = rsqrtf(ss + EPS);

        const int c_  = ic >> 3, icl = ic & 7;
        const int at_ = oc >> 5, ln_ = oc & 31;
        const size_t abase = (size_t)(b * NCH + c_) * NST * 128
                           + (size_t)at_ * 64 + ln_;
#pragma unroll
        for (int k = 0; k < NTAP; ++k) {
            const int dz = k / 9, r9 = k - dz * 9, dy = r9 / 3, dx = r9 - dy * 3;
            const int j  = dz * 3 + dx;
            int mm, hh;
            if (j < 8) { mm = 3 * (j >> 1) + dy; hh = j & 1; }
            else       { mm = (dy == 2) ? 13 : 12; hh = (dy == 1) ? 1 : 0; }
            const size_t tex = abase + (size_t)mm * 128 + (size_t)hh * 32;
            wA3[tex * 8 + icl] = bf16r(v[k] * d);
        }
        // pad slot (m=13, h=1) = 0
        {
            const size_t tex = abase + (size_t)13 * 128 + 32;
            wA3[tex * 8 + icl] = 0;
        }
    } else {
        const int j2   = gid - 128;
        const int zidx = j2 % 34;
        const int ch   = (j2 / 34) & 7;
        const int b    = j2 / 272;
        int4* slab = xP + (size_t)(b * NCH + ch) * SLABTEX;
        const int4 z4 = make_int4(0, 0, 0, 0);

        if (zidx >= 32) {
            const int base = (zidx == 32) ? 0 : 1090 * 33;
            for (int p = t; p < 34 * 33; p += 256) slab[base + p] = z4;
            return;
        }
        const float* xc = x + ((size_t)b * CIN + ch * CH) * SPATIAL + zidx * 1024;
        int4* dst = slab + (34 + 33 * zidx) * 33;
        for (int p = t; p < 33 * 33; p += 256) {
            const int r  = p / 33;
            const int cx = p - r * 33;
            int4 vv = z4;
            if (r < 32 && cx > 0) {
                const float* s = xc + r * 32 + (cx - 1);
                vv.x = (int)pack2(s[0 * SPATIAL], s[1 * SPATIAL]);
                vv.y = (int)pack2(s[2 * SPATIAL], s[3 * SPATIAL]);
                vv.z = (int)pack2(s[4 * SPATIAL], s[5 * SPATIAL]);
                vv.w = (int)pack2(s[6 * SPATIAL], s[7 * SPATIAL]);
            }
            dst[p] = vv;
        }
    }
}

// ---------------------------------------------------------------------------
// conv3d_mfma: 16-WAVE version (4 waves/SIMD TLP). grid = 256 (bid&7=b,
// bid>>3=z), 1024 threads. Same block tile (64oc x 1024sp), same LDS layout
// and dy-phase B reuse as R12; wave tile = 32oc x 128sp:
//   oh = wv&1 (oc half), rg = wv>>1 (sp row group, rows rg*4..rg*4+3).
// acc = 4 x f32x16 = 64 VGPR; __launch_bounds__(1024,4) caps VGPR at 128
// so all 16 waves are co-resident (4 independent streams per SIMD to
// overlap LDS-read, DMA and MFMA pipes — the missing TLP).
// ---------------------------------------------------------------------------
__global__ __launch_bounds__(1024, 4) void conv3d_mfma(
        const int4* __restrict__ xP,
        const int4* __restrict__ wA3,
        float* __restrict__ out) {
    const int bid = blockIdx.x;
    const int b = bid & 7, z = bid >> 3;
    const int t    = threadIdx.x;
    const int l    = t & 63;
    const int ln31 = t & 31;
    const int h2   = (t >> 5) & 1;
    const int wv   = t >> 6;          // 0..15
    const int oh   = wv & 1;          // oc half (0: oc 0-31, 1: oc 32-63)
    const int rg   = wv >> 1;         // row group 0..7

    __shared__ int4 smem[2 * XBUFT + 2 * ABUFT];

    // 6 row-fragment byte offsets within the X window (rows rg*4 .. rg*4+5)
    int rowQ[6];
#pragma unroll
    for (int q = 0; q < 6; ++q)
        rowQ[q] = ((rg * 4 + q) * 33 + ln31) * 16;
    // per-lane (dz,dx) offsets for col s: j = 2s + h2
    int offc[4];
#pragma unroll
    for (int s = 0; s < 4; ++s) {
        const int j = 2 * s + h2;
        offc[s] = ((j / 3) * 1089 + (j % 3)) * 16;
    }
    const int off8 = (2 * 1089 + 2) * 16;          // j==8 (dz=2,dx=2)

    // ---- stage chunk c (X window + A) into buffer buf: pure DMA ----
    auto stage = [&](int c, int buf) {
        const int4* xsrc = xP + (size_t)(b * NCH + c) * SLABTEX + (size_t)z * 1089;
        const int4* asrc = wA3 + (size_t)(b * NCH + c) * ABUFT;
        int4* lx = smem + buf * XBUFT;
        int4* la = smem + 2 * XBUFT + buf * ABUFT;
#pragma unroll
        for (int i = 0; i < 4; ++i) {
            const int p = i * 1024 + t;
            if (p < WINTEX) gload_lds16(xsrc + p, lx + (p & ~63));
        }
#pragma unroll
        for (int i = 0; i < 2; ++i) {
            const int p = i * 1024 + t;
            if (p < ABUFT) gload_lds16(asrc + p, la + (p & ~63));
        }
    };

    f32x16 acc[4];
#pragma unroll
    for (int j = 0; j < 4; ++j)
#pragma unroll
        for (int r = 0; r < 16; ++r) acc[j][r] = 0.0f;

    stage(0, 0);
    __syncthreads();

    for (int c = 0; c < NCH; ++c) {
        if (c + 1 < NCH) stage(c + 1, (c + 1) & 1);    // async, lands during MFMA
        const char* Xb = (const char*)(smem + (c & 1) * XBUFT);
        const char* Ab = (const char*)(smem + 2 * XBUFT + (c & 1) * ABUFT);

#pragma unroll
        for (int s = 0; s < 4; ++s) {
            // 6 shared row fragments (rows rg*4 .. rg*4+5) for this col
            int4 F[6];
#pragma unroll
            for (int q = 0; q < 6; ++q)
                F[q] = *(const int4*)(Xb + rowQ[q] + offc[s]);
            // dy phases: load A per phase (keeps VGPR pressure low)
#pragma unroll
            for (int dy = 0; dy < 3; ++dy) {
                const bf16x8 a = *(const bf16x8*)(
                    Ab + (3 * s + dy) * 2048 + oh * 1024 + l * 16);
#pragma unroll
                for (int st = 0; st < 4; ++st)
                    acc[st] = __builtin_amdgcn_mfma_f32_32x32x16_bf16(
                        a, *(const bf16x8*)&F[st + dy], acc[st], 0, 0, 0);
            }
        }

        // ---- tail: j==8 taps. m=12: (dy0 h0, dy1 h1); m=13: (dy2 h0, pad) ----
        {
            int4 T1[4], T2[4];
#pragma unroll
            for (int st = 0; st < 4; ++st) {
                T1[st] = *(const int4*)(Xb + rowQ[st] + h2 * (33 * 16) + off8);
                T2[st] = *(const int4*)(Xb + rowQ[st + 2] + off8);
            }
            const bf16x8 a12 = *(const bf16x8*)(Ab + 12 * 2048 + oh * 1024 + l * 16);
            const bf16x8 a13 = *(const bf16x8*)(Ab + 13 * 2048 + oh * 1024 + l * 16);
#pragma unroll
            for (int st = 0; st < 4; ++st)
                acc[st] = __builtin_amdgcn_mfma_f32_32x32x16_bf16(
                    a12, *(const bf16x8*)&T1[st], acc[st], 0, 0, 0);
#pragma unroll
            for (int st = 0; st < 4; ++st)
                acc[st] = __builtin_amdgcn_mfma_f32_32x32x16_bf16(
                    a13, *(const bf16x8*)&T2[st], acc[st], 0, 0, 0);
        }
        __syncthreads();
    }

    // ---- epilogue: 32x32 D layout col=lane&31, row=(r&3)+8*(r>>2)+4*(l>>5) ---
    float* ob = out + (size_t)b * COUT * SPATIAL + (size_t)z * 1024;
#pragma unroll
    for (int st = 0; st < 4; ++st) {
        const int sp = (rg * 4 + st) * 32 + ln31;
#pragma unroll
        for (int r = 0; r < 16; ++r) {
            const int oc = oh * 32 + (r & 3) + 8 * (r >> 2) + 4 * h2;
            ob[(size_t)oc * SPATIAL + sp] = acc[st][r];
        }
    }
}

// ---------------------------------------------------------------------------
extern "C" void kernel_launch(void* const* d_in, const int* in_sizes, int n_in,
                              void* d_out, int out_size, void* d_ws, size_t ws_size,
                              hipStream_t stream) {
    const float* x        = (const float*)d_in[0];
    const float* w        = (const float*)d_in[1];
    const float* filter_w = (const float*)d_in[2];
    const float* filter_b = (const float*)d_in[3];
    const float* mod_w    = (const float*)d_in[4];
    const float* mod_b    = (const float*)d_in[5];
    const float* bank     = (const float*)d_in[6];
    float* out = (float*)d_out;

    int4* xP = (int4*)d_ws;
    unsigned short* wA3 = (unsigned short*)(xP + XP_TEXELS);

    prep_fused<<<128 + 34 * 8 * 8, 256, 0, stream>>>(
        x, w, filter_w, filter_b, mod_w, mod_b, bank, xP, wA3);
    conv3d_mfma<<<256, 1024, 0, stream>>>(xP, (const int4*)wA3, out);
}

// Round 14
// 88.333 us; speedup vs baseline: 1.0147x; 1.0147x over previous
//
#include <hip/hip_runtime.h>
#include <math.h>

#define BS 8
#define CIN 64
#define COUT 64
#define SDIM 512
#define NBANK 4
#define DSZ 32
#define SPATIAL (DSZ*DSZ*DSZ)
#define NTAP 27
#define CH 8                   // ic per chunk
#define NCH 8                  // chunks
#define NST 14                 // K=16 steps per chunk (27 taps + 1 pad half)
// xP slab (per b,ch): 1124 rows x 33 texels (texel = 16B = 8 ic bf16)
#define SLABTEX (1124*33)
#define WINTEX 3301            // full-plane 3-z window
#define XBUFT 3304             // LDS X buffer texels (padded)
#define ABUFT 1792             // LDS A buffer texels: 14 steps * 128
#define XP_TEXELS (64*SLABTEX)
constexpr float EPS = 1e-8f;

typedef short bf16x8 __attribute__((ext_vector_type(8)));
typedef float f32x16 __attribute__((ext_vector_type(16)));

__device__ __forceinline__ unsigned pack2(float a, float b) {
    unsigned ua = __float_as_uint(a);
    unsigned ub = __float_as_uint(b);
    ua = (ua + 0x7fffu + ((ua >> 16) & 1u)) >> 16;
    ub = (ub + 0x7fffu + ((ub >> 16) & 1u)) & 0xffff0000u;
    return ua | ub;
}
__device__ __forceinline__ unsigned short bf16r(float f) {
    unsigned u = __float_as_uint(f);
    u = (u + 0x7fffu + ((u >> 16) & 1u)) >> 16;
    return (unsigned short)u;
}
__device__ __forceinline__ void gload_lds16(const int4* g, int4* l) {
    __builtin_amdgcn_global_load_lds(
        (const __attribute__((address_space(1))) unsigned int*)(const void*)g,
        (__attribute__((address_space(3))) unsigned int*)(void*)l, 16, 0, 0);
}
// raw workgroup barrier: hardware sync + compiler memory fence, but NO
// implicit s_waitcnt vmcnt(0)/lgkmcnt(0) drain (unlike __syncthreads()).
__device__ __forceinline__ void phase_barrier() {
    asm volatile("s_barrier" ::: "memory");
}

// ---------------------------------------------------------------------------
// prep_fused: blocks [0,128): weights (+inline style); [128,128+2176): xform.
// A K-step ordering (dy-phase structure for B-fragment reuse in conv):
//   tap t: dz=t/9, dy=(t%9)/3, dx=t%3, j=dz*3+dx.
//   j<8 : m = 3*(j>>1)+dy, h = j&1          (cols s=0..3, phases dy=0..2)
//   j==8: dy0 -> (m=12,h=0); dy1 -> (m=12,h=1); dy2 -> (m=13,h=0)
//   (m=13,h=1) = zero pad.
// A texel = ((b*8+c)*14 + m)*128 + (oc>>5)*64 + h*32 + (oc&31); elem = ic&7.
// ---------------------------------------------------------------------------
__global__ __launch_bounds__(256) void prep_fused(
        const float* __restrict__ x,
        const float* __restrict__ w,
        const float* __restrict__ filter_w,
        const float* __restrict__ filter_b,
        const float* __restrict__ mod_w,
        const float* __restrict__ mod_b,
        const float* __restrict__ bank,
        int4* __restrict__ xP,
        unsigned short* __restrict__ wA3) {
    const int gid = blockIdx.x;
    const int t   = threadIdx.x;

    if (gid < 128) {
        const int b   = gid >> 4;
        const int oc  = (gid & 15) * 4 + (t >> 6);
        const int ic  = t & 63;
        const float* wb = w + b * SDIM;

        float fw[NBANK];
#pragma unroll
        for (int n = 0; n < NBANK; ++n) {
            float p = 0.0f;
            const float* fr = filter_w + n * SDIM;
#pragma unroll
            for (int k = 0; k < 8; ++k) p += wb[ic + 64 * k] * fr[ic + 64 * k];
#pragma unroll
            for (int off = 32; off >= 1; off >>= 1) p += __shfl_xor(p, off, 64);
            fw[n] = p + filter_b[n];
        }
        float mx = fmaxf(fmaxf(fw[0], fw[1]), fmaxf(fw[2], fw[3]));
        float se = 0.0f;
#pragma unroll
        for (int n = 0; n < NBANK; ++n) { fw[n] = expf(fw[n] - mx); se += fw[n]; }
        const float inv = 1.0f / se;
        const float f0 = fw[0] * inv, f1 = fw[1] * inv, f2 = fw[2] * inv, f3 = fw[3] * inv;

        float m = mod_b[ic];
        {
            const float4* wv4 = (const float4*)wb;
            const float4* mr4 = (const float4*)(mod_w + ic * SDIM);
            for (int j = 0; j < SDIM / 4; ++j) {
                float4 a = wv4[j], c = mr4[j];
                m += a.x * c.x + a.y * c.y + a.z * c.z + a.w * c.w;
            }
        }

        const float* b0 = bank + (size_t)((0 * COUT + oc) * CIN + ic) * NTAP;
        const float* b1 = bank + (size_t)((1 * COUT + oc) * CIN + ic) * NTAP;
        const float* b2 = bank + (size_t)((2 * COUT + oc) * CIN + ic) * NTAP;
        const float* b3 = bank + (size_t)((3 * COUT + oc) * CIN + ic) * NTAP;

        float v[NTAP];
        float ss = 0.0f;
#pragma unroll
        for (int k = 0; k < NTAP; ++k) {
            float tv = f0 * b0[k] + f1 * b1[k] + f2 * b2[k] + f3 * b3[k];
            tv *= m;
            v[k] = tv;
            ss += tv * tv;
        }
#pragma unroll
        for (int off = 32; off >= 1; off >>= 1) ss += __shfl_xor(ss, off, 64);
        const float d = rsqrtf(ss + EPS);

        const int c_  = ic >> 3, icl = ic & 7;
        const int at_ = oc >> 5, ln_ = oc & 31;
        const size_t abase = (size_t)(b * NCH + c_) * NST * 128
                           + (size_t)at_ * 64 + ln_;
#pragma unroll
        for (int k = 0; k < NTAP; ++k) {
            const int dz = k / 9, r9 = k - dz * 9, dy = r9 / 3, dx = r9 - dy * 3;
            const int j  = dz * 3 + dx;
            int mm, hh;
            if (j < 8) { mm = 3 * (j >> 1) + dy; hh = j & 1; }
            else       { mm = (dy == 2) ? 13 : 12; hh = (dy == 1) ? 1 : 0; }
            const size_t tex = abase + (size_t)mm * 128 + (size_t)hh * 32;
            wA3[tex * 8 + icl] = bf16r(v[k] * d);
        }
        // pad slot (m=13, h=1) = 0
        {
            const size_t tex = abase + (size_t)13 * 128 + 32;
            wA3[tex * 8 + icl] = 0;
        }
    } else {
        const int j2   = gid - 128;
        const int zidx = j2 % 34;
        const int ch   = (j2 / 34) & 7;
        const int b    = j2 / 272;
        int4* slab = xP + (size_t)(b * NCH + ch) * SLABTEX;
        const int4 z4 = make_int4(0, 0, 0, 0);

        if (zidx >= 32) {
            const int base = (zidx == 32) ? 0 : 1090 * 33;
            for (int p = t; p < 34 * 33; p += 256) slab[base + p] = z4;
            return;
        }
        const float* xc = x + ((size_t)b * CIN + ch * CH) * SPATIAL + zidx * 1024;
        int4* dst = slab + (34 + 33 * zidx) * 33;
        for (int p = t; p < 33 * 33; p += 256) {
            const int r  = p / 33;
            const int cx = p - r * 33;
            int4 vv = z4;
            if (r < 32 && cx > 0) {
                const float* s = xc + r * 32 + (cx - 1);
                vv.x = (int)pack2(s[0 * SPATIAL], s[1 * SPATIAL]);
                vv.y = (int)pack2(s[2 * SPATIAL], s[3 * SPATIAL]);
                vv.z = (int)pack2(s[4 * SPATIAL], s[5 * SPATIAL]);
                vv.w = (int)pack2(s[6 * SPATIAL], s[7 * SPATIAL]);
            }
            dst[p] = vv;
        }
    }
}

// ---------------------------------------------------------------------------
// conv3d_mfma: R12 (dy-reuse) restructured as a PHASE-BARRIER pipeline
// (T3+T5 template, adapted). grid = 256 (bid&7=b, bid>>3=z), 512 threads.
// Per chunk: stage(c+1) fully issued at phase 1, then 5 phases of
//   {ds_read cluster -> raw s_barrier -> setprio(1) MFMA cluster setprio(0)
//    -> raw s_barrier};
// one counted s_waitcnt vmcnt(0) at chunk end (DMAs aged the whole chunk).
// __syncthreads (which drains vmcnt/lgkm at EVERY use) appears nowhere in
// the main loop.
// ---------------------------------------------------------------------------
__global__ __launch_bounds__(512, 2) void conv3d_mfma(
        const int4* __restrict__ xP,
        const int4* __restrict__ wA3,
        float* __restrict__ out) {
    const int bid = blockIdx.x;
    const int b = bid & 7, z = bid >> 3;
    const int t    = threadIdx.x;
    const int l    = t & 63;
    const int ln31 = t & 31;
    const int h2   = (t >> 5) & 1;
    const int wv   = t >> 6;

    __shared__ int4 smem[2 * XBUFT + 2 * ABUFT];

    // 6 row-fragment byte offsets within the X window (rows wv*4 .. wv*4+5)
    int rowQ[6];
#pragma unroll
    for (int q = 0; q < 6; ++q)
        rowQ[q] = ((wv * 4 + q) * 33 + ln31) * 16;
    // per-lane (dz,dx) offsets for col s: j = 2s + h2
    int offc[4];
#pragma unroll
    for (int s = 0; s < 4; ++s) {
        const int j = 2 * s + h2;
        offc[s] = ((j / 3) * 1089 + (j % 3)) * 16;
    }
    const int off8 = (2 * 1089 + 2) * 16;          // j==8 (dz=2,dx=2)

    // ---- stage chunk c (X window + A) into buffer buf: pure DMA, 11 instr ----
    auto stage = [&](int c, int buf) {
        const int4* xsrc = xP + (size_t)(b * NCH + c) * SLABTEX + (size_t)z * 1089;
        const int4* asrc = wA3 + (size_t)(b * NCH + c) * ABUFT;
        int4* lx = smem + buf * XBUFT;
        int4* la = smem + 2 * XBUFT + buf * ABUFT;
#pragma unroll
        for (int i = 0; i < 7; ++i) {
            const int p = i * 512 + t;
            if (p < WINTEX) gload_lds16(xsrc + p, lx + (p & ~63));
        }
#pragma unroll
        for (int i = 0; i < 4; ++i) {
            const int p = i * 512 + t;
            if (p < ABUFT) gload_lds16(asrc + p, la + (p & ~63));
        }
    };

    f32x16 acc[2][4];
#pragma unroll
    for (int i = 0; i < 2; ++i)
#pragma unroll
        for (int j = 0; j < 4; ++j)
#pragma unroll
            for (int r = 0; r < 16; ++r) acc[i][j][r] = 0.0f;

    stage(0, 0);
    asm volatile("s_waitcnt vmcnt(0)" ::: "memory");
    phase_barrier();

    for (int c = 0; c < NCH; ++c) {
        // issue ALL of next chunk's staging DMAs up front: they age through
        // the whole chunk (~10-15k cy) so the chunk-end vmcnt(0) is ~free.
        if (c + 1 < NCH) stage(c + 1, (c + 1) & 1);
        const char* Xb = (const char*)(smem + (c & 1) * XBUFT);
        const char* Ab = (const char*)(smem + 2 * XBUFT + (c & 1) * ABUFT);

        // ---- phases 1-4: dy-reuse columns ----
#pragma unroll
        for (int s = 0; s < 4; ++s) {
            int4 F[6];
#pragma unroll
            for (int q = 0; q < 6; ++q)
                F[q] = *(const int4*)(Xb + rowQ[q] + offc[s]);
            bf16x8 a0[2], a1[2], a2[2];
#pragma unroll
            for (int at = 0; at < 2; ++at) {
                a0[at] = *(const bf16x8*)(Ab + (3 * s + 0) * 2048 + at * 1024 + l * 16);
                a1[at] = *(const bf16x8*)(Ab + (3 * s + 1) * 2048 + at * 1024 + l * 16);
                a2[at] = *(const bf16x8*)(Ab + (3 * s + 2) * 2048 + at * 1024 + l * 16);
            }
            phase_barrier();                       // reads issued; sync phase
            __builtin_amdgcn_s_setprio(1);
#pragma unroll
            for (int at = 0; at < 2; ++at)
#pragma unroll
                for (int st = 0; st < 4; ++st)
                    acc[at][st] = __builtin_amdgcn_mfma_f32_32x32x16_bf16(
                        a0[at], *(const bf16x8*)&F[st], acc[at][st], 0, 0, 0);
#pragma unroll
            for (int at = 0; at < 2; ++at)
#pragma unroll
                for (int st = 0; st < 4; ++st)
                    acc[at][st] = __builtin_amdgcn_mfma_f32_32x32x16_bf16(
                        a1[at], *(const bf16x8*)&F[st + 1], acc[at][st], 0, 0, 0);
#pragma unroll
            for (int at = 0; at < 2; ++at)
#pragma unroll
                for (int st = 0; st < 4; ++st)
                    acc[at][st] = __builtin_amdgcn_mfma_f32_32x32x16_bf16(
                        a2[at], *(const bf16x8*)&F[st + 2], acc[at][st], 0, 0, 0);
            __builtin_amdgcn_s_setprio(0);
            phase_barrier();                       // MFMA cluster done
        }

        // ---- phase 5: tail (j==8 taps) ----
        {
            int4 T1[4], T2[4];
#pragma unroll
            for (int st = 0; st < 4; ++st) {
                T1[st] = *(const int4*)(Xb + rowQ[st] + h2 * (33 * 16) + off8);
                T2[st] = *(const int4*)(Xb + rowQ[st + 2] + off8);
            }
            bf16x8 a12[2], a13[2];
#pragma unroll
            for (int at = 0; at < 2; ++at) {
                a12[at] = *(const bf16x8*)(Ab + 12 * 2048 + at * 1024 + l * 16);
                a13[at] = *(const bf16x8*)(Ab + 13 * 2048 + at * 1024 + l * 16);
            }
            phase_barrier();
            __builtin_amdgcn_s_setprio(1);
#pragma unroll
            for (int at = 0; at < 2; ++at)
#pragma unroll
                for (int st = 0; st < 4; ++st)
                    acc[at][st] = __builtin_amdgcn_mfma_f32_32x32x16_bf16(
                        a12[at], *(const bf16x8*)&T1[st], acc[at][st], 0, 0, 0);
#pragma unroll
            for (int at = 0; at < 2; ++at)
#pragma unroll
                for (int st = 0; st < 4; ++st)
                    acc[at][st] = __builtin_amdgcn_mfma_f32_32x32x16_bf16(
                        a13[at], *(const bf16x8*)&T2[st], acc[at][st], 0, 0, 0);
            __builtin_amdgcn_s_setprio(0);
        }

        // chunk boundary: next buffer must be fully staged before any wave
        // reads it. DMAs were issued at phase 1 -> this wait is ~aged-out.
        asm volatile("s_waitcnt vmcnt(0)" ::: "memory");
        phase_barrier();
    }

    // ---- epilogue: 32x32 D layout col=lane&31, row=(r&3)+8*(r>>2)+4*(l>>5) ---
    float* ob = out + (size_t)b * COUT * SPATIAL + (size_t)z * 1024;
#pragma unroll
    for (int at = 0; at < 2; ++at)
#pragma unroll
        for (int st = 0; st < 4; ++st) {
            const int sp = (wv * 4 + st) * 32 + ln31;
#pragma unroll
            for (int r = 0; r < 16; ++r) {
                const int oc = at * 32 + (r & 3) + 8 * (r >> 2) + 4 * h2;
                ob[(size_t)oc * SPATIAL + sp] = acc[at][st][r];
            }
        }
}

// ---------------------------------------------------------------------------
extern "C" void kernel_launch(void* const* d_in, const int* in_sizes, int n_in,
                              void* d_out, int out_size, void* d_ws, size_t ws_size,
                              hipStream_t stream) {
    const float* x        = (const float*)d_in[0];
    const float* w        = (const float*)d_in[1];
    const float* filter_w = (const float*)d_in[2];
    const float* filter_b = (const float*)d_in[3];
    const float* mod_w    = (const float*)d_in[4];
    const float* mod_b    = (const float*)d_in[5];
    const float* bank     = (const float*)d_in[6];
    float* out = (float*)d_out;

    int4* xP = (int4*)d_ws;
    unsigned short* wA3 = (unsigned short*)(xP + XP_TEXELS);

    prep_fused<<<128 + 34 * 8 * 8, 256, 0, stream>>>(
        x, w, filter_w, filter_b, mod_w, mod_b, bank, xP, wA3);
    conv3d_mfma<<<256, 512, 0, stream>>>(xP, (const int4*)wA3, out);
}

// Round 15
// 80.111 us; speedup vs baseline: 1.1189x; 1.1026x over previous
//
#include <hip/hip_runtime.h>
#include <math.h>

#define BS 8
#define CIN 64
#define COUT 64
#define SDIM 512
#define NBANK 4
#define DSZ 32
#define SPATIAL (DSZ*DSZ*DSZ)
#define NTAP 27
#define CH 8                   // ic per chunk
#define NCH 8                  // chunks
#define NST 14                 // K=16 steps per chunk (28 taps / 2 taps per step)
// xP slab (per b,ch): 1124 rows x 33 texels (texel = 16B = 8 ic bf16)
#define SLABTEX (1124*33)
#define WINTEX 3301            // full-plane 3-z window
#define XBUFT 3304             // LDS X buffer texels (padded)
#define ABUFT 1792             // LDS A buffer texels: 14 steps * 128
#define XP_TEXELS (64*SLABTEX)
constexpr float EPS = 1e-8f;

typedef short bf16x8 __attribute__((ext_vector_type(8)));
typedef float f32x16 __attribute__((ext_vector_type(16)));

__device__ __forceinline__ unsigned pack2(float a, float b) {
    unsigned ua = __float_as_uint(a);
    unsigned ub = __float_as_uint(b);
    ua = (ua + 0x7fffu + ((ua >> 16) & 1u)) >> 16;
    ub = (ub + 0x7fffu + ((ub >> 16) & 1u)) & 0xffff0000u;
    return ua | ub;
}
__device__ __forceinline__ unsigned short bf16r(float f) {
    unsigned u = __float_as_uint(f);
    u = (u + 0x7fffu + ((u >> 16) & 1u)) >> 16;
    return (unsigned short)u;
}
__device__ __forceinline__ void gload_lds16(const int4* g, int4* l) {
    __builtin_amdgcn_global_load_lds(
        (const __attribute__((address_space(1))) unsigned int*)(const void*)g,
        (__attribute__((address_space(3))) unsigned int*)(void*)l, 16, 0, 0);
}
// LDS byte address (32-bit) of a generic pointer known to be in LDS
__device__ __forceinline__ unsigned lds_u32(const void* p) {
    return (unsigned)(unsigned long long)
        (const __attribute__((address_space(3))) char*)(const char*)p;
}
// raw ds_read_b128: NO compiler-tracked wait; we count lgkmcnt ourselves
__device__ __forceinline__ void dsread16(int4& d, unsigned addr) {
    asm volatile("ds_read_b128 %0, %1" : "=v"(d) : "v"(addr));
}

// ---------------------------------------------------------------------------
// prep_fused: blocks [0,128): weights (+inline style); [128,128+2176): xform.
// Weights path de-redundified: style softmax computed once (wave 0) and
// mod[ic] once (threads 0-63) into LDS; the 4 oc-waves consume them.
// Weight layout wA3 (texels of 8 ic bf16):
//   tex = ((b*8+chunk)*14 + (tap>>1))*128 + (oc>>5)*64 + (tap&1)*32 + (oc&31)
// 64-lane ds_read at (step s, at): lane l gets (oc = at*32+(l&31), tap = 2s+(l>>5))
// = the 32x32x16 A fragment. tap 27 written as zeros (K-pad).
// ---------------------------------------------------------------------------
__global__ __launch_bounds__(256) void prep_fused(
        const float* __restrict__ x,
        const float* __restrict__ w,
        const float* __restrict__ filter_w,
        const float* __restrict__ filter_b,
        const float* __restrict__ mod_w,
        const float* __restrict__ mod_b,
        const float* __restrict__ bank,
        int4* __restrict__ xP,
        unsigned short* __restrict__ wA3) {
    const int gid = blockIdx.x;
    const int t   = threadIdx.x;

    if (gid < 128) {
        const int b   = gid >> 4;
        const int oc  = (gid & 15) * 4 + (t >> 6);
        const int ic  = t & 63;
        const float* wb = w + b * SDIM;

        __shared__ float sfw[NBANK];
        __shared__ float smod[CIN];

        if (t < 64) {
            // ---- style softmax: wave 0 only ----
            float fw[NBANK];
#pragma unroll
            for (int n = 0; n < NBANK; ++n) {
                float p = 0.0f;
                const float* fr = filter_w + n * SDIM;
#pragma unroll
                for (int k = 0; k < 8; ++k) p += wb[t + 64 * k] * fr[t + 64 * k];
#pragma unroll
                for (int off = 32; off >= 1; off >>= 1) p += __shfl_xor(p, off, 64);
                fw[n] = p + filter_b[n];
            }
            float mx = fmaxf(fmaxf(fw[0], fw[1]), fmaxf(fw[2], fw[3]));
            float se = 0.0f;
#pragma unroll
            for (int n = 0; n < NBANK; ++n) { fw[n] = expf(fw[n] - mx); se += fw[n]; }
            const float inv = 1.0f / se;
            if (t < NBANK) sfw[t] = fw[t] * inv;

            // ---- mod[ic]: one 512-dot per thread, once per block ----
            float m = mod_b[t];
            const float4* wv4 = (const float4*)wb;
            const float4* mr4 = (const float4*)(mod_w + t * SDIM);
            for (int j = 0; j < SDIM / 4; ++j) {
                float4 a = wv4[j], c = mr4[j];
                m += a.x * c.x + a.y * c.y + a.z * c.z + a.w * c.w;
            }
            smod[t] = m;
        }
        __syncthreads();

        const float f0 = sfw[0], f1 = sfw[1], f2 = sfw[2], f3 = sfw[3];
        const float m  = smod[ic];

        const float* b0 = bank + (size_t)((0 * COUT + oc) * CIN + ic) * NTAP;
        const float* b1 = bank + (size_t)((1 * COUT + oc) * CIN + ic) * NTAP;
        const float* b2 = bank + (size_t)((2 * COUT + oc) * CIN + ic) * NTAP;
        const float* b3 = bank + (size_t)((3 * COUT + oc) * CIN + ic) * NTAP;

        float v[NTAP];
        float ss = 0.0f;
#pragma unroll
        for (int k = 0; k < NTAP; ++k) {
            float tv = f0 * b0[k] + f1 * b1[k] + f2 * b2[k] + f3 * b3[k];
            tv *= m;
            v[k] = tv;
            ss += tv * tv;
        }
#pragma unroll
        for (int off = 32; off >= 1; off >>= 1) ss += __shfl_xor(ss, off, 64);
        const float d = rsqrtf(ss + EPS);

        const int c_  = ic >> 3, icl = ic & 7;
        const int at_ = oc >> 5, ln_ = oc & 31;
#pragma unroll
        for (int k = 0; k < 28; ++k) {
            const float val = (k < NTAP) ? v[k] * d : 0.0f;
            const size_t tex = ((size_t)(b * NCH + c_) * NST + (k >> 1)) * 128
                             + (size_t)at_ * 64 + (size_t)(k & 1) * 32 + ln_;
            wA3[tex * 8 + icl] = bf16r(val);
        }
    } else {
        const int j2   = gid - 128;
        const int zidx = j2 % 34;
        const int ch   = (j2 / 34) & 7;
        const int b    = j2 / 272;
        int4* slab = xP + (size_t)(b * NCH + ch) * SLABTEX;
        const int4 z4 = make_int4(0, 0, 0, 0);

        if (zidx >= 32) {
            const int base = (zidx == 32) ? 0 : 1090 * 33;
            for (int p = t; p < 34 * 33; p += 256) slab[base + p] = z4;
            return;
        }
        const float* xc = x + ((size_t)b * CIN + ch * CH) * SPATIAL + zidx * 1024;
        int4* dst = slab + (34 + 33 * zidx) * 33;
        for (int p = t; p < 33 * 33; p += 256) {
            const int r  = p / 33;
            const int cx = p - r * 33;
            int4 vv = z4;
            if (r < 32 && cx > 0) {
                const float* s = xc + r * 32 + (cx - 1);
                vv.x = (int)pack2(s[0 * SPATIAL], s[1 * SPATIAL]);
                vv.y = (int)pack2(s[2 * SPATIAL], s[3 * SPATIAL]);
                vv.z = (int)pack2(s[4 * SPATIAL], s[5 * SPATIAL]);
                vv.w = (int)pack2(s[6 * SPATIAL], s[7 * SPATIAL]);
            }
            dst[p] = vv;
        }
    }
}

// ---------------------------------------------------------------------------
// conv3d_mfma: R11 verbatim (best measured: 60.2 us, MfmaUtil 42%).
// grid = 256 (bid&7=b, bid>>3=z), 512 threads (8 waves), 1 block/CU.
// Inline-asm ds_reads + counted lgkmcnt(6) per K-step; X + A double-buffered
// in LDS via global_load_lds DMA issued at chunk start (aged across chunk).
// ---------------------------------------------------------------------------
__global__ __launch_bounds__(512, 2) void conv3d_mfma(
        const int4* __restrict__ xP,
        const int4* __restrict__ wA3,
        float* __restrict__ out) {
    const int bid = blockIdx.x;
    const int b = bid & 7, z = bid >> 3;
    const int t    = threadIdx.x;
    const int l    = t & 63;
    const int ln31 = t & 31;
    const int h2   = (t >> 5) & 1;
    const int wv   = t >> 6;

    __shared__ int4 smem[2 * XBUFT + 2 * ABUFT];

    // B tap offsets: step s covers taps {2s, 2s+1}; this lane's tap = 2s+h2.
    int offB[NST];
#pragma unroll
    for (int s = 0; s < NST; ++s) {
        int tap = 2 * s + h2;
        if (tap > 26) tap = 0;               // tap 27: A is zero, addr just valid
        const int dz = tap / 9, r = tap - dz * 9, dy = r / 3, dx = r - dy * 3;
        offB[s] = (dz * 1089 + dy * 33 + dx) * 16;
    }
    int baseB[4];
#pragma unroll
    for (int st = 0; st < 4; ++st)
        baseB[st] = ((wv * 4 + st) * 33 + ln31) * 16;   // y = wv*4+st, x = ln31

    // ---- stage chunk c (X window + A) into buffer buf: pure DMA ----
    auto stage = [&](int c, int buf) {
        const int4* xsrc = xP + (size_t)(b * NCH + c) * SLABTEX + (size_t)z * 1089;
        const int4* asrc = wA3 + (size_t)(b * NCH + c) * ABUFT;
        int4* lx = smem + buf * XBUFT;
        int4* la = smem + 2 * XBUFT + buf * ABUFT;
#pragma unroll
        for (int i = 0; i < 7; ++i) {
            const int p = i * 512 + t;
            if (p < WINTEX) gload_lds16(xsrc + p, lx + (p & ~63));
        }
#pragma unroll
        for (int i = 0; i < 4; ++i) {
            const int p = i * 512 + t;
            if (p < ABUFT) gload_lds16(asrc + p, la + (p & ~63));
        }
    };

    f32x16 acc[2][4];
#pragma unroll
    for (int i = 0; i < 2; ++i)
#pragma unroll
        for (int j = 0; j < 4; ++j)
#pragma unroll
            for (int r = 0; r < 16; ++r) acc[i][j][r] = 0.0f;

    stage(0, 0);
    __syncthreads();

    for (int c = 0; c < NCH; ++c) {
        if (c + 1 < NCH) stage(c + 1, (c + 1) & 1);    // async, lands during MFMA

        // LDS byte addresses for this chunk's buffers
        const unsigned xb = lds_u32(smem + (c & 1) * XBUFT);
        const unsigned ab = lds_u32(smem + 2 * XBUFT + (c & 1) * ABUFT);
        const unsigned aAddr = ab + (unsigned)(l * 16);
        unsigned bAddr[4];
#pragma unroll
        for (int st = 0; st < 4; ++st) bAddr[st] = xb + (unsigned)baseB[st];

        int4 A0[2], B0[4], A1[2], B1[4];

        // issue the 6 raw ds_reads for step s into the given set
        auto issue = [&](int s, int4 (&A)[2], int4 (&B)[4]) {
            const unsigned a0 = aAddr + (unsigned)(s * 2048);
            dsread16(A[0], a0);
            dsread16(A[1], a0 + 1024u);
#pragma unroll
            for (int st = 0; st < 4; ++st)
                dsread16(B[st], bAddr[st] + (unsigned)offB[s]);
        };
        auto mfma8 = [&](int4 (&A)[2], int4 (&B)[4]) {
#pragma unroll
            for (int at = 0; at < 2; ++at)
#pragma unroll
                for (int st = 0; st < 4; ++st)
                    acc[at][st] = __builtin_amdgcn_mfma_f32_32x32x16_bf16(
                        *(const bf16x8*)&A[at], *(const bf16x8*)&B[st],
                        acc[at][st], 0, 0, 0);
        };

        issue(0, A0, B0);
#pragma unroll
        for (int s = 0; s < NST; ++s) {
            if (s + 1 < NST) {
                if ((s & 1) == 0) issue(s + 1, A1, B1);
                else              issue(s + 1, A0, B0);
                asm volatile("s_waitcnt lgkmcnt(6)" ::: "memory");
            } else {
                asm volatile("s_waitcnt lgkmcnt(0)" ::: "memory");
            }
            __builtin_amdgcn_sched_barrier(0);         // rule #18 fence
            if ((s & 1) == 0) mfma8(A0, B0);
            else              mfma8(A1, B1);
        }
        __syncthreads();
    }

    // ---- epilogue: 32x32 D layout col=lane&31, row=(r&3)+8*(r>>2)+4*(l>>5) ---
    float* ob = out + (size_t)b * COUT * SPATIAL + (size_t)z * 1024;
#pragma unroll
    for (int at = 0; at < 2; ++at)
#pragma unroll
        for (int st = 0; st < 4; ++st) {
            const int sp = (wv * 4 + st) * 32 + ln31;
#pragma unroll
            for (int r = 0; r < 16; ++r) {
                const int oc = at * 32 + (r & 3) + 8 * (r >> 2) + 4 * h2;
                ob[(size_t)oc * SPATIAL + sp] = acc[at][st][r];
            }
        }
}

// ---------------------------------------------------------------------------
extern "C" void kernel_launch(void* const* d_in, const int* in_sizes, int n_in,
                              void* d_out, int out_size, void* d_ws, size_t ws_size,
                              hipStream_t stream) {
    const float* x        = (const float*)d_in[0];
    const float* w        = (const float*)d_in[1];
    const float* filter_w = (const float*)d_in[2];
    const float* filter_b = (const float*)d_in[3];
    const float* mod_w    = (const float*)d_in[4];
    const float* mod_b    = (const float*)d_in[5];
    const float* bank     = (const float*)d_in[6];
    float* out = (float*)d_out;

    int4* xP = (int4*)d_ws;
    unsigned short* wA3 = (unsigned short*)(xP + XP_TEXELS);

    prep_fused<<<128 + 34 * 8 * 8, 256, 0, stream>>>(
        x, w, filter_w, filter_b, mod_w, mod_b, bank, xP, wA3);
    conv3d_mfma<<<256, 512, 0, stream>>>(xP, (const int4*)wA3, out);
}